// Round 14
// baseline (184.253 us; speedup 1.0000x reference)
//
#include <hip/hip_runtime.h>

#define DIM 128
#define EPB_A 8192    // edges per histscat block
#define BSH 10        // bucket = id >> 10 (1024 nodes per bucket)
#define BNODES 1024
#define CAPB 18432    // per-bucket slab capacity (mean 16384, +16 sigma)
#define NBMAX 128

// ---------- u8 -> f32 helpers ----------
#if __has_builtin(__builtin_amdgcn_cvt_f32_ubyte0)
#define CVTU0 __builtin_amdgcn_cvt_f32_ubyte0
#define CVTU1 __builtin_amdgcn_cvt_f32_ubyte1
#else
__device__ __forceinline__ float CVTU0(unsigned u) { return (float)(u & 0xffu); }
__device__ __forceinline__ float CVTU1(unsigned u) { return (float)((u >> 8) & 0xffu); }
#endif

// ---------- build phase (as round 11/13) ----------

__global__ __launch_bounds__(512) void histscat(const int2* __restrict__ edges, int E,
                                                int* __restrict__ bcnt,
                                                int* __restrict__ scnt,
                                                unsigned* __restrict__ ebuck,
                                                unsigned short* __restrict__ sbuck,
                                                int NB) {
    __shared__ int hdst[NBMAX], hsrc[NBMAX], cdst[NBMAX], csrc[NBMAX];
    int tid = threadIdx.x;
    if (tid < NBMAX) { hdst[tid] = 0; hsrc[tid] = 0; }
    __syncthreads();
    int base = blockIdx.x * EPB_A;
    int cnt = min(EPB_A, E - base);
    int2 ed[16];
    #pragma unroll
    for (int i = 0; i < 16; ++i) {
        int idx = tid + i * 512;
        ed[i] = (idx < cnt) ? edges[base + idx] : make_int2(-1, -1);
    }
    #pragma unroll
    for (int i = 0; i < 16; ++i) {
        if (ed[i].x >= 0) {
            atomicAdd(&hdst[ed[i].y >> BSH], 1);
            atomicAdd(&hsrc[ed[i].x >> BSH], 1);
        }
    }
    __syncthreads();
    if (tid < NB) {
        if (hdst[tid] > 0) cdst[tid] = atomicAdd(&bcnt[tid], hdst[tid]);
        if (hsrc[tid] > 0) csrc[tid] = atomicAdd(&scnt[tid], hsrc[tid]);
    }
    __syncthreads();
    #pragma unroll
    for (int i = 0; i < 16; ++i) {
        if (ed[i].x >= 0) {
            int bd = ed[i].y >> BSH, bs = ed[i].x >> BSH;
            int p = atomicAdd(&cdst[bd], 1);
            ebuck[(size_t)bd * CAPB + p] =
                ((unsigned)ed[i].x << BSH) | (unsigned)(ed[i].y & (BNODES - 1));
            int q = atomicAdd(&csrc[bs], 1);
            sbuck[(size_t)bs * CAPB + q] = (unsigned short)(ed[i].x & (BNODES - 1));
        }
    }
}

__global__ __launch_bounds__(1024) void passD(const unsigned short* __restrict__ sbuck,
                                              const int* __restrict__ scnt,
                                              float* __restrict__ dinv, int N) {
    __shared__ int cnt[BNODES];
    int b = blockIdx.x, tid = threadIdx.x;
    int m = scnt[b];
    const unsigned short* sb = sbuck + (size_t)b * CAPB;
    cnt[tid] = 0;
    __syncthreads();
    for (int i = tid; i < m; i += 1024) atomicAdd(&cnt[sb[i]], 1);
    __syncthreads();
    int node = (b << BSH) + tid;
    if (node < N) dinv[node] = rsqrtf((float)(cnt[tid] + 1));   // +1 self-loop
}

__global__ void conv_q8(const float4* __restrict__ xin, const float* __restrict__ dinv,
                        uint2* __restrict__ qx, float* __restrict__ scx, int n8) {
    int i = blockIdx.x * blockDim.x + threadIdx.x;
    if (i >= n8) return;
    int node = i >> 4, ln = i & 15;
    float dv = dinv[node];
    float4 v0 = xin[2 * i], v1 = xin[2 * i + 1];
    float y0 = dv * v0.x, y1 = dv * v0.y, y2 = dv * v0.z, y3 = dv * v0.w;
    float y4 = dv * v1.x, y5 = dv * v1.y, y6 = dv * v1.z, y7 = dv * v1.w;
    float mx = fmaxf(fmaxf(fmaxf(fabsf(y0), fabsf(y1)), fmaxf(fabsf(y2), fabsf(y3))),
                     fmaxf(fmaxf(fabsf(y4), fabsf(y5)), fmaxf(fabsf(y6), fabsf(y7))));
    mx = fmaxf(mx, __shfl_xor(mx, 1));
    mx = fmaxf(mx, __shfl_xor(mx, 2));
    mx = fmaxf(mx, __shfl_xor(mx, 4));
    mx = fmaxf(mx, __shfl_xor(mx, 8));
    float inv = (mx > 0.f) ? 127.f / mx : 0.f;
    unsigned q0 = (unsigned)(__float2int_rn(y0 * inv) + 128);
    unsigned q1 = (unsigned)(__float2int_rn(y1 * inv) + 128);
    unsigned q2 = (unsigned)(__float2int_rn(y2 * inv) + 128);
    unsigned q3 = (unsigned)(__float2int_rn(y3 * inv) + 128);
    unsigned q4 = (unsigned)(__float2int_rn(y4 * inv) + 128);
    unsigned q5 = (unsigned)(__float2int_rn(y5 * inv) + 128);
    unsigned q6 = (unsigned)(__float2int_rn(y6 * inv) + 128);
    unsigned q7 = (unsigned)(__float2int_rn(y7 * inv) + 128);
    uint2 ov;
    ov.x = q0 | (q1 << 8) | (q2 << 16) | (q3 << 24);
    ov.y = q4 | (q5 << 8) | (q6 << 16) | (q7 << 24);
    qx[(size_t)node * 16 + ln] = ov;
    if (ln == 0) scx[node] = mx * (1.f / 127.f);
}

__global__ __launch_bounds__(1024) void passC(const unsigned* __restrict__ ebuck,
                                              const int* __restrict__ bcnt,
                                              int* __restrict__ rowoff,
                                              int* __restrict__ csr_src,
                                              int N, int E, int NB) {
    __shared__ int cnt[BNODES];
    __shared__ int fill[BNODES];
    __shared__ int s[BNODES];
    __shared__ int red[128];
    int b = blockIdx.x, tid = threadIdx.x;
    if (tid < 128) red[tid] = (tid < NB && tid < b) ? bcnt[tid] : 0;
    __syncthreads();
    for (int off = 64; off > 0; off >>= 1) {
        if (tid < off) red[tid] += red[tid + off];
        __syncthreads();
    }
    int eb0 = red[0];
    int m = bcnt[b];
    const unsigned* eb = ebuck + (size_t)b * CAPB;
    cnt[tid] = 0;
    __syncthreads();
    for (int i = tid; i < m; i += 1024)
        atomicAdd(&cnt[eb[i] & (BNODES - 1u)], 1);
    __syncthreads();
    int node = (b << BSH) + tid;
    int val = (node < N) ? cnt[tid] + 1 : 0;   // +1 self-loop
    s[tid] = val;
    __syncthreads();
    for (int off = 1; off < 1024; off <<= 1) {
        int t = (tid >= off) ? s[tid - off] : 0;
        __syncthreads();
        s[tid] += t;
        __syncthreads();
    }
    int excl = s[tid] - val;
    int csrb = eb0 + (b << BSH);
    if (node < N) rowoff[node] = csrb + excl;
    fill[tid] = excl;
    if (b == NB - 1 && tid == 0) rowoff[N] = E + N;
    __syncthreads();
    for (int i = tid; i < m; i += 1024) {
        unsigned u = eb[i];
        int p = atomicAdd(&fill[u & (BNODES - 1u)], 1);
        csr_src[csrb + p] = (int)(u >> BSH);
    }
    __syncthreads();
    if (node < N) csr_src[csrb + fill[tid]] = node;   // self-loop last
}

// ---------- layer: shuffle-free, lane-owns-dims ----------
// Wave = 1 node; lane owns dims (2*lane, 2*lane+1). Edge srcs preloaded into
// lane regs (coalesced, covers deg<=64); per-slot src via v_readlane -> SGPR
// (no LDS), scale via uniform scalar load, row load saddr + 2*lane. Bias corr
// is a uniform scalar sum. Zero cross-lane ops in the edge loop.

#define SLOT4(j)                                                              \
    int s0 = __builtin_amdgcn_readlane(msrc, (j));                            \
    int s1 = __builtin_amdgcn_readlane(msrc, (j) + 1);                        \
    int s2 = __builtin_amdgcn_readlane(msrc, (j) + 2);                        \
    int s3 = __builtin_amdgcn_readlane(msrc, (j) + 3);                        \
    float c0 = scin[s0];                                                      \
    float c1 = ((j) + 1 < mm) ? scin[s1] : 0.f;                               \
    float c2 = ((j) + 2 < mm) ? scin[s2] : 0.f;                               \
    float c3 = ((j) + 3 < mm) ? scin[s3] : 0.f;                               \
    unsigned r0 = *(const unsigned short*)(qin + (((size_t)(unsigned)s0) << 7) + 2 * lane); \
    unsigned r1 = *(const unsigned short*)(qin + (((size_t)(unsigned)s1) << 7) + 2 * lane); \
    unsigned r2 = *(const unsigned short*)(qin + (((size_t)(unsigned)s2) << 7) + 2 * lane); \
    unsigned r3 = *(const unsigned short*)(qin + (((size_t)(unsigned)s3) << 7) + 2 * lane); \
    a0 = fmaf(c0, CVTU0(r0), a0); a1 = fmaf(c0, CVTU1(r0), a1);               \
    a0 = fmaf(c1, CVTU0(r1), a0); a1 = fmaf(c1, CVTU1(r1), a1);               \
    a0 = fmaf(c2, CVTU0(r2), a0); a1 = fmaf(c2, CVTU1(r2), a1);               \
    a0 = fmaf(c3, CVTU0(r3), a0); a1 = fmaf(c3, CVTU1(r3), a1);               \
    if (BIASED) corr += (c0 + c1) + (c2 + c3);

template<int BIASED, int LAST>
__global__ __launch_bounds__(256) void gcn_layer(
    const unsigned char* __restrict__ qin, const float* __restrict__ scin,
    const int* __restrict__ rowoff, const int* __restrict__ csr_src,
    const float* __restrict__ dinv,
    const float* __restrict__ w, const float* __restrict__ bia,
    void* __restrict__ qout, float* __restrict__ scout, int N) {
    int node = blockIdx.x * 4 + (threadIdx.x >> 6);
    if (node >= N) return;
    node = __builtin_amdgcn_readfirstlane(node);
    int lane = threadIdx.x & 63;
    int start = rowoff[node];
    int mm = rowoff[node + 1] - start;     // degree incl self-loop, >= 1
    // preload: lane j holds csr index of edge j (clamped; covers deg<=64)
    int msrc = csr_src[start + min(lane, mm - 1)];
    float a0 = 0.f, a1 = 0.f, corr = 0.f;

    int nb = min((mm + 3) >> 2, 16);       // bands of 4 edges, uniform loop
    for (int b = 0; b < nb; ++b) {
        SLOT4(4 * b);
    }
    // rare tail (deg > 64): uniform dependent loads
    for (int o = 64; o < mm; ++o) {
        int sx = __builtin_amdgcn_readfirstlane(csr_src[start + o]);
        float sc = scin[sx];
        unsigned r = *(const unsigned short*)(qin + (((size_t)(unsigned)sx) << 7) + 2 * lane);
        a0 = fmaf(sc, CVTU0(r), a0);
        a1 = fmaf(sc, CVTU1(r), a1);
        if (BIASED) corr += sc;
    }

    if (BIASED) {   // corr is wave-uniform: no reduction needed
        a0 = fmaf(-128.f, corr, a0);
        a1 = fmaf(-128.f, corr, a1);
    }

    float dn = dinv[node];
    float2 wv = ((const float2*)w)[lane];
    float2 bv = ((const float2*)bia)[lane];
    float o0 = fmaf(a0, dn * wv.x, bv.x);
    float o1 = fmaf(a1, dn * wv.y, bv.y);
    if (!LAST) {   // relu, pre-scale by dinv, unbiased u8 quant for next layer
        o0 = dn * fmaxf(o0, 0.f);
        o1 = dn * fmaxf(o1, 0.f);
        float mx = fmaxf(o0, o1);
        mx = fmaxf(mx, __shfl_xor(mx, 1));
        mx = fmaxf(mx, __shfl_xor(mx, 2));
        mx = fmaxf(mx, __shfl_xor(mx, 4));
        mx = fmaxf(mx, __shfl_xor(mx, 8));
        mx = fmaxf(mx, __shfl_xor(mx, 16));
        mx = fmaxf(mx, __shfl_xor(mx, 32));
        float inv = (mx > 0.f) ? 255.f / mx : 0.f;
        unsigned q0 = (unsigned)__float2int_rn(o0 * inv);
        unsigned q1 = (unsigned)__float2int_rn(o1 * inv);
        *(unsigned short*)((unsigned char*)qout + (size_t)node * DIM + 2 * lane) =
            (unsigned short)(q0 | (q1 << 8));
        if (lane == 0) scout[node] = mx * (1.f / 255.f);
    } else {       // fp32 out
        ((float2*)qout)[(size_t)node * 64 + lane] = make_float2(o0, o1);
    }
}

// ---------- launch ----------

static inline size_t align256(size_t x) { return (x + 255) & ~(size_t)255; }

extern "C" void kernel_launch(void* const* d_in, const int* in_sizes, int n_in,
                              void* d_out, int out_size, void* d_ws, size_t ws_size,
                              hipStream_t stream) {
    const int2*  edges = (const int2*)d_in[0];
    const float* x     = (const float*)d_in[1];
    const float* w1    = (const float*)d_in[2];
    const float* b1    = (const float*)d_in[3];
    const float* w2    = (const float*)d_in[4];
    const float* b2    = (const float*)d_in[5];
    float* out = (float*)d_out;

    const int E = in_sizes[0] / 2;
    const int N = in_sizes[1] / DIM;
    const int TOT = E + N;
    const int NB   = (N + BNODES - 1) >> BSH;   // 1024-node buckets
    const int nblk = (E + EPB_A - 1) / EPB_A;   // histscat blocks

    // workspace carve-up
    char* p = (char*)d_ws;
    int*            bcnt    = (int*)p;             // NB, zeroed
    int*            scnt    = bcnt + NB;           // NB, zeroed (contiguous)
    p += align256((size_t)2 * NB * 4);
    float*          dinv    = (float*)p;           p += align256((size_t)N * 4);
    float*          scX     = (float*)p;           p += align256((size_t)N * 4);
    float*          scH     = (float*)p;           p += align256((size_t)N * 4);
    int*            rowoff  = (int*)p;             p += align256((size_t)(N + 1) * 4);
    unsigned*       ebuck   = (unsigned*)p;        p += align256((size_t)NB * CAPB * 4);
    unsigned short* sbuck   = (unsigned short*)p;  p += align256((size_t)NB * CAPB * 2);
    int*            csr_src = (int*)p;             p += align256((size_t)TOT * 4);
    unsigned char*  qx      = (unsigned char*)p;   p += align256((size_t)N * DIM);
    unsigned char*  qh      = (unsigned char*)p;   p += align256((size_t)N * DIM);

    const int TPB = 256;
    int n8  = N * DIM / 8;
    int nbC = (n8 + TPB - 1) / TPB;

    hipMemsetAsync(bcnt, 0, (size_t)2 * NB * 4, stream);
    histscat<<<nblk, 512, 0, stream>>>(edges, E, bcnt, scnt, ebuck, sbuck, NB);
    passD<<<NB, 1024, 0, stream>>>(sbuck, scnt, dinv, N);
    conv_q8<<<nbC, TPB, 0, stream>>>((const float4*)x, dinv, (uint2*)qx, scX, n8);
    passC<<<NB, 1024, 0, stream>>>(ebuck, bcnt, rowoff, csr_src, N, E, NB);

    int nbL = (N + 3) / 4;
    gcn_layer<1, 0><<<nbL, TPB, 0, stream>>>(qx, scX, rowoff, csr_src, dinv,
                                             w1, b1, qh, scH, N);
    gcn_layer<0, 1><<<nbL, TPB, 0, stream>>>(qh, scH, rowoff, csr_src, dinv,
                                             w2, b2, out, nullptr, N);
}

// Round 15
// 167.099 us; speedup vs baseline: 1.1027x; 1.1027x over previous
//
#include <hip/hip_runtime.h>

#define DIM 128
#define EPB_A 8192    // edges per histscat block
#define BSH 10        // bucket = id >> 10 (1024 nodes per bucket)
#define BNODES 1024
#define CAPB 18432    // per-bucket slab capacity (mean 16384, +16 sigma)
#define NBMAX 128
#define PSTR 25       // padded-csr stride: [0]=deg, [1..24]=srcs (deg<=24 fast path)

// ---------- u8 -> f32 helpers ----------
#if __has_builtin(__builtin_amdgcn_cvt_f32_ubyte0)
#define CVTU0 __builtin_amdgcn_cvt_f32_ubyte0
#define CVTU1 __builtin_amdgcn_cvt_f32_ubyte1
#define CVTU2 __builtin_amdgcn_cvt_f32_ubyte2
#define CVTU3 __builtin_amdgcn_cvt_f32_ubyte3
#else
__device__ __forceinline__ float CVTU0(unsigned u) { return (float)(u & 0xffu); }
__device__ __forceinline__ float CVTU1(unsigned u) { return (float)((u >> 8) & 0xffu); }
__device__ __forceinline__ float CVTU2(unsigned u) { return (float)((u >> 16) & 0xffu); }
__device__ __forceinline__ float CVTU3(unsigned u) { return (float)((u >> 24) & 0xffu); }
#endif

// ---------- build phase ----------

__global__ __launch_bounds__(512) void histscat(const int2* __restrict__ edges, int E,
                                                int* __restrict__ bcnt,
                                                int* __restrict__ scnt,
                                                unsigned* __restrict__ ebuck,
                                                unsigned short* __restrict__ sbuck,
                                                int NB) {
    __shared__ int hdst[NBMAX], hsrc[NBMAX], cdst[NBMAX], csrc[NBMAX];
    int tid = threadIdx.x;
    if (tid < NBMAX) { hdst[tid] = 0; hsrc[tid] = 0; }
    __syncthreads();
    int base = blockIdx.x * EPB_A;
    int cnt = min(EPB_A, E - base);
    int2 ed[16];
    #pragma unroll
    for (int i = 0; i < 16; ++i) {
        int idx = tid + i * 512;
        ed[i] = (idx < cnt) ? edges[base + idx] : make_int2(-1, -1);
    }
    #pragma unroll
    for (int i = 0; i < 16; ++i) {
        if (ed[i].x >= 0) {
            atomicAdd(&hdst[ed[i].y >> BSH], 1);
            atomicAdd(&hsrc[ed[i].x >> BSH], 1);
        }
    }
    __syncthreads();
    if (tid < NB) {
        if (hdst[tid] > 0) cdst[tid] = atomicAdd(&bcnt[tid], hdst[tid]);
        if (hsrc[tid] > 0) csrc[tid] = atomicAdd(&scnt[tid], hsrc[tid]);
    }
    __syncthreads();
    #pragma unroll
    for (int i = 0; i < 16; ++i) {
        if (ed[i].x >= 0) {
            int bd = ed[i].y >> BSH, bs = ed[i].x >> BSH;
            int p = atomicAdd(&cdst[bd], 1);
            ebuck[(size_t)bd * CAPB + p] =
                ((unsigned)ed[i].x << BSH) | (unsigned)(ed[i].y & (BNODES - 1));
            int q = atomicAdd(&csrc[bs], 1);
            sbuck[(size_t)bs * CAPB + q] = (unsigned short)(ed[i].x & (BNODES - 1));
        }
    }
}

__global__ __launch_bounds__(1024) void passD(const unsigned short* __restrict__ sbuck,
                                              const int* __restrict__ scnt,
                                              float* __restrict__ dinv, int N) {
    __shared__ int cnt[BNODES];
    int b = blockIdx.x, tid = threadIdx.x;
    int m = scnt[b];
    const unsigned short* sb = sbuck + (size_t)b * CAPB;
    cnt[tid] = 0;
    __syncthreads();
    for (int i = tid; i < m; i += 1024) atomicAdd(&cnt[sb[i]], 1);
    __syncthreads();
    int node = (b << BSH) + tid;
    if (node < N) dinv[node] = rsqrtf((float)(cnt[tid] + 1));   // +1 self-loop
}

__global__ void conv_q8(const float4* __restrict__ xin, const float* __restrict__ dinv,
                        uint2* __restrict__ qx, float* __restrict__ scx, int n8) {
    int i = blockIdx.x * blockDim.x + threadIdx.x;
    if (i >= n8) return;
    int node = i >> 4, ln = i & 15;
    float dv = dinv[node];
    float4 v0 = xin[2 * i], v1 = xin[2 * i + 1];
    float y0 = dv * v0.x, y1 = dv * v0.y, y2 = dv * v0.z, y3 = dv * v0.w;
    float y4 = dv * v1.x, y5 = dv * v1.y, y6 = dv * v1.z, y7 = dv * v1.w;
    float mx = fmaxf(fmaxf(fmaxf(fabsf(y0), fabsf(y1)), fmaxf(fabsf(y2), fabsf(y3))),
                     fmaxf(fmaxf(fabsf(y4), fabsf(y5)), fmaxf(fabsf(y6), fabsf(y7))));
    mx = fmaxf(mx, __shfl_xor(mx, 1));
    mx = fmaxf(mx, __shfl_xor(mx, 2));
    mx = fmaxf(mx, __shfl_xor(mx, 4));
    mx = fmaxf(mx, __shfl_xor(mx, 8));
    float inv = (mx > 0.f) ? 127.f / mx : 0.f;
    unsigned q0 = (unsigned)(__float2int_rn(y0 * inv) + 128);
    unsigned q1 = (unsigned)(__float2int_rn(y1 * inv) + 128);
    unsigned q2 = (unsigned)(__float2int_rn(y2 * inv) + 128);
    unsigned q3 = (unsigned)(__float2int_rn(y3 * inv) + 128);
    unsigned q4 = (unsigned)(__float2int_rn(y4 * inv) + 128);
    unsigned q5 = (unsigned)(__float2int_rn(y5 * inv) + 128);
    unsigned q6 = (unsigned)(__float2int_rn(y6 * inv) + 128);
    unsigned q7 = (unsigned)(__float2int_rn(y7 * inv) + 128);
    uint2 ov;
    ov.x = q0 | (q1 << 8) | (q2 << 16) | (q3 << 24);
    ov.y = q4 | (q5 << 8) | (q6 << 16) | (q7 << 24);
    qx[(size_t)node * 16 + ln] = ov;
    if (ln == 0) scx[node] = mx * (1.f / 127.f);
}

// One block (1024 thr) per dst-bucket: padded pcsr (deg<=24) + overflow CSR.
__global__ __launch_bounds__(1024) void passC(const unsigned* __restrict__ ebuck,
                                              const int* __restrict__ bcnt,
                                              int* __restrict__ rowoff,
                                              int* __restrict__ csr_src,
                                              int* __restrict__ pcsr,
                                              int N, int E, int NB) {
    __shared__ int cnt[BNODES];
    __shared__ int fill[BNODES];
    __shared__ int sbase[BNODES];
    __shared__ int s[BNODES];
    __shared__ int red[128];
    int b = blockIdx.x, tid = threadIdx.x;
    if (tid < 128) red[tid] = (tid < NB && tid < b) ? bcnt[tid] : 0;
    __syncthreads();
    for (int off = 64; off > 0; off >>= 1) {
        if (tid < off) red[tid] += red[tid + off];
        __syncthreads();
    }
    int eb0 = red[0];
    int m = bcnt[b];
    const unsigned* eb = ebuck + (size_t)b * CAPB;
    cnt[tid] = 0;
    __syncthreads();
    for (int i = tid; i < m; i += 1024)
        atomicAdd(&cnt[eb[i] & (BNODES - 1u)], 1);
    __syncthreads();
    int node = (b << BSH) + tid;
    int val = (node < N) ? cnt[tid] + 1 : 0;   // degree incl self-loop
    s[tid] = val;
    __syncthreads();
    for (int off = 1; off < 1024; off <<= 1) {
        int t = (tid >= off) ? s[tid - off] : 0;
        __syncthreads();
        s[tid] += t;
        __syncthreads();
    }
    int excl = s[tid] - val;
    int csrb = eb0 + (b << BSH);
    if (node < N) {
        rowoff[node] = csrb + excl;
        pcsr[(size_t)node * PSTR] = val;       // deg slot (>24 -> slow path)
    }
    fill[tid] = excl;
    sbase[tid] = excl;
    if (b == NB - 1 && tid == 0) rowoff[N] = E + N;
    __syncthreads();
    for (int i = tid; i < m; i += 1024) {
        unsigned u = eb[i];
        int loc = (int)(u & (BNODES - 1u));
        int p = atomicAdd(&fill[loc], 1);
        int src = (int)(u >> BSH);
        if (cnt[loc] <= 23) {                  // fast-path node: padded entry
            int gn = (b << BSH) + loc;
            pcsr[(size_t)gn * PSTR + 1 + (p - sbase[loc])] = src;
        } else {                               // overflow node: bucket CSR
            csr_src[csrb + p] = src;
        }
    }
    __syncthreads();
    if (node < N) {                            // self-loop last
        if (cnt[tid] <= 23) pcsr[(size_t)node * PSTR + 1 + cnt[tid]] = node;
        else                csr_src[csrb + fill[tid]] = node;
    }
}

// ---------- layer: padded metadata, 2-hop chain ----------
// Wave = 1 node. Fast path (deg<=24, ~97%): ONE coalesced pcsr preload gives
// all edge srcs (addr computed from node id -- no rowoff hop); deg via
// uniform s_load. 6 unconditional slots. Slow path: old rowoff/csr gather.

#define ACCQ(r, sc) do {                                                   \
    a0 = fmaf(sc, CVTU0(r.x), a0); a1 = fmaf(sc, CVTU1(r.x), a1);          \
    a2 = fmaf(sc, CVTU2(r.x), a2); a3 = fmaf(sc, CVTU3(r.x), a3);          \
    a4 = fmaf(sc, CVTU0(r.y), a4); a5 = fmaf(sc, CVTU1(r.y), a5);          \
    a6 = fmaf(sc, CVTU2(r.y), a6); a7 = fmaf(sc, CVTU3(r.y), a7);          \
} while (0)

#define SLOT(j) do {                                                       \
    int  sj = __shfl(msrc, gb + (j));                                      \
    float sc = __shfl(msc, gb + (j));                                      \
    uint2 r = *(const uint2*)(qbase + (((unsigned)sj) << 7));              \
    ACCQ(r, sc);                                                           \
} while (0)

template<int BIASED, int LAST>
__global__ __launch_bounds__(256) void gcn_layer(
    const uint2* __restrict__ qin, const float* __restrict__ scin,
    const int* __restrict__ rowoff, const int* __restrict__ csr_src,
    const int* __restrict__ pcsr, const float* __restrict__ dinv,
    const float* __restrict__ w, const float* __restrict__ bia,
    void* __restrict__ qout, float* __restrict__ scout, int N) {
    int node = blockIdx.x * 4 + (threadIdx.x >> 6);
    if (node >= N) return;
    node = __builtin_amdgcn_readfirstlane(node);
    int lane = threadIdx.x & 63;
    int h  = lane >> 4;        // group (4 concurrent edges)
    int ln = lane & 15;        // 16 lanes x uint2(8B) = 128B row
    int gb = lane & 48;        // first lane of this group
    float a0=0,a1=0,a2=0,a3=0,a4=0,a5=0,a6=0,a7=0;
    const char* qbase = (const char*)qin + (ln << 3);

    int mm = pcsr[(size_t)node * PSTR];        // uniform scalar load (deg)
    int off = h + 4 * ln;                      // this lane's edge offset (bijective 0..63)
    float msc;
    int msrc;
    float corr_t = 0.f;

    if (mm <= 24) {
        // --- fast path: padded preload, no rowoff hop ---
        int v = pcsr[(size_t)node * PSTR + 1 + min(off, 23)];
        msrc = min(max(v, 0), N - 1);          // clamp (unwritten slots = poison)
        msc = (off < mm) ? scin[msrc] : 0.f;
        SLOT(0); SLOT(1); SLOT(2); SLOT(3); SLOT(4); SLOT(5);
    } else {
        // --- slow path (~3% of nodes): original rowoff/csr gather ---
        int start = rowoff[node];
        int offc = min(off, mm - 1);
        msrc = csr_src[start + offc];
        msc = (off < mm) ? scin[msrc] : 0.f;
        SLOT(0); SLOT(1); SLOT(2); SLOT(3); SLOT(4); SLOT(5);
        SLOT(6); SLOT(7); SLOT(8); SLOT(9); SLOT(10);
        SLOT(11); SLOT(12); SLOT(13); SLOT(14); SLOT(15);
        for (int o = 64 + h; o < mm; o += 4) {     // deg > 64
            int sx = csr_src[start + o];
            float sc = scin[sx];
            uint2 c = *(const uint2*)(qbase + (((unsigned)sx) << 7));
            ACCQ(c, sc);
            if (BIASED && ln == 0) corr_t += sc;
        }
    }

    a0+=__shfl_xor(a0,16); a1+=__shfl_xor(a1,16); a2+=__shfl_xor(a2,16); a3+=__shfl_xor(a3,16);
    a4+=__shfl_xor(a4,16); a5+=__shfl_xor(a5,16); a6+=__shfl_xor(a6,16); a7+=__shfl_xor(a7,16);
    a0+=__shfl_xor(a0,32); a1+=__shfl_xor(a1,32); a2+=__shfl_xor(a2,32); a3+=__shfl_xor(a3,32);
    a4+=__shfl_xor(a4,32); a5+=__shfl_xor(a5,32); a6+=__shfl_xor(a6,32); a7+=__shfl_xor(a7,32);

    if (BIASED) {
        // each in-range preloaded lane holds one edge's scale exactly once
        float cv = msc + corr_t;
        cv += __shfl_xor(cv, 1);  cv += __shfl_xor(cv, 2);
        cv += __shfl_xor(cv, 4);  cv += __shfl_xor(cv, 8);
        cv += __shfl_xor(cv, 16); cv += __shfl_xor(cv, 32);
        float c = 128.f * cv;
        a0 -= c; a1 -= c; a2 -= c; a3 -= c; a4 -= c; a5 -= c; a6 -= c; a7 -= c;
    }

    if (h == 0) {
        float dn = dinv[node];
        float4 w0 = ((const float4*)w)[ln * 2],   w1 = ((const float4*)w)[ln * 2 + 1];
        float4 b0 = ((const float4*)bia)[ln * 2], b1 = ((const float4*)bia)[ln * 2 + 1];
        float o0 = fmaf(a0, dn * w0.x, b0.x), o1 = fmaf(a1, dn * w0.y, b0.y);
        float o2 = fmaf(a2, dn * w0.z, b0.z), o3 = fmaf(a3, dn * w0.w, b0.w);
        float o4 = fmaf(a4, dn * w1.x, b1.x), o5 = fmaf(a5, dn * w1.y, b1.y);
        float o6 = fmaf(a6, dn * w1.z, b1.z), o7 = fmaf(a7, dn * w1.w, b1.w);
        if (!LAST) {   // relu, pre-scale by dinv, unbiased uint8 quant for next layer
            o0 = dn * fmaxf(o0, 0.f); o1 = dn * fmaxf(o1, 0.f);
            o2 = dn * fmaxf(o2, 0.f); o3 = dn * fmaxf(o3, 0.f);
            o4 = dn * fmaxf(o4, 0.f); o5 = dn * fmaxf(o5, 0.f);
            o6 = dn * fmaxf(o6, 0.f); o7 = dn * fmaxf(o7, 0.f);
            float mx = fmaxf(fmaxf(fmaxf(o0, o1), fmaxf(o2, o3)),
                             fmaxf(fmaxf(o4, o5), fmaxf(o6, o7)));
            mx = fmaxf(mx, __shfl_xor(mx, 1));
            mx = fmaxf(mx, __shfl_xor(mx, 2));
            mx = fmaxf(mx, __shfl_xor(mx, 4));
            mx = fmaxf(mx, __shfl_xor(mx, 8));
            float inv = (mx > 0.f) ? 255.f / mx : 0.f;
            unsigned q0 = (unsigned)__float2int_rn(o0 * inv);
            unsigned q1 = (unsigned)__float2int_rn(o1 * inv);
            unsigned q2 = (unsigned)__float2int_rn(o2 * inv);
            unsigned q3 = (unsigned)__float2int_rn(o3 * inv);
            unsigned q4 = (unsigned)__float2int_rn(o4 * inv);
            unsigned q5 = (unsigned)__float2int_rn(o5 * inv);
            unsigned q6 = (unsigned)__float2int_rn(o6 * inv);
            unsigned q7 = (unsigned)__float2int_rn(o7 * inv);
            uint2 ov;
            ov.x = q0 | (q1 << 8) | (q2 << 16) | (q3 << 24);
            ov.y = q4 | (q5 << 8) | (q6 << 16) | (q7 << 24);
            ((uint2*)qout)[(size_t)node * 16 + ln] = ov;
            if (ln == 0) scout[node] = mx * (1.f / 255.f);
        } else {       // fp32 out
            ((float4*)qout)[(size_t)node * 32 + ln * 2]     = make_float4(o0, o1, o2, o3);
            ((float4*)qout)[(size_t)node * 32 + ln * 2 + 1] = make_float4(o4, o5, o6, o7);
        }
    }
}

// ---------- launch ----------

static inline size_t align256(size_t x) { return (x + 255) & ~(size_t)255; }

extern "C" void kernel_launch(void* const* d_in, const int* in_sizes, int n_in,
                              void* d_out, int out_size, void* d_ws, size_t ws_size,
                              hipStream_t stream) {
    const int2*  edges = (const int2*)d_in[0];
    const float* x     = (const float*)d_in[1];
    const float* w1    = (const float*)d_in[2];
    const float* b1    = (const float*)d_in[3];
    const float* w2    = (const float*)d_in[4];
    const float* b2    = (const float*)d_in[5];
    float* out = (float*)d_out;

    const int E = in_sizes[0] / 2;
    const int N = in_sizes[1] / DIM;
    const int TOT = E + N;
    const int NB   = (N + BNODES - 1) >> BSH;   // 1024-node buckets
    const int nblk = (E + EPB_A - 1) / EPB_A;   // histscat blocks

    // workspace carve-up
    char* p = (char*)d_ws;
    int*            bcnt    = (int*)p;             // NB, zeroed
    int*            scnt    = bcnt + NB;           // NB, zeroed (contiguous)
    p += align256((size_t)2 * NB * 4);
    float*          dinv    = (float*)p;           p += align256((size_t)N * 4);
    float*          scX     = (float*)p;           p += align256((size_t)N * 4);
    float*          scH     = (float*)p;           p += align256((size_t)N * 4);
    int*            rowoff  = (int*)p;             p += align256((size_t)(N + 1) * 4);
    unsigned*       ebuck   = (unsigned*)p;        p += align256((size_t)NB * CAPB * 4);
    unsigned short* sbuck   = (unsigned short*)p;  p += align256((size_t)NB * CAPB * 2);
    int*            csr_src = (int*)p;             p += align256((size_t)TOT * 4);
    int*            pcsr    = (int*)p;             p += align256((size_t)N * PSTR * 4);
    uint2*          qx      = (uint2*)p;           p += align256((size_t)N * DIM);
    uint2*          qh      = (uint2*)p;           p += align256((size_t)N * DIM);

    const int TPB = 256;
    int n8  = N * DIM / 8;
    int nbC = (n8 + TPB - 1) / TPB;

    hipMemsetAsync(bcnt, 0, (size_t)2 * NB * 4, stream);
    histscat<<<nblk, 512, 0, stream>>>(edges, E, bcnt, scnt, ebuck, sbuck, NB);
    passD<<<NB, 1024, 0, stream>>>(sbuck, scnt, dinv, N);
    conv_q8<<<nbC, TPB, 0, stream>>>((const float4*)x, dinv, qx, scX, n8);
    passC<<<NB, 1024, 0, stream>>>(ebuck, bcnt, rowoff, csr_src, pcsr, N, E, NB);

    int nbL = (N + 3) / 4;
    gcn_layer<1, 0><<<nbL, TPB, 0, stream>>>(qx, scX, rowoff, csr_src, pcsr, dinv,
                                             w1, b1, qh, scH, N);
    gcn_layer<0, 1><<<nbL, TPB, 0, stream>>>(qh, scH, rowoff, csr_src, pcsr, dinv,
                                             w2, b2, out, nullptr, N);
}